// Round 16
// baseline (121.258 us; speedup 1.0000x reference)
//
#include <hip/hip_runtime.h>

using u16 = unsigned short;
using u32 = unsigned int;

typedef __attribute__((ext_vector_type(8))) short bf16x8;
typedef __attribute__((ext_vector_type(8))) unsigned short u16x8;
typedef __attribute__((ext_vector_type(4))) float f32x4;
typedef __attribute__((ext_vector_type(16))) float f32x16;
typedef __attribute__((ext_vector_type(4))) u32 u32x4;

constexpr int Bb   = 2;
constexpr int Ss   = 4096;
constexpr int Dd   = 512;
constexpr int Hh   = 16;
constexpr int DQK  = 64;
constexpr int LQ   = 1024;   // S / BPL
constexpr int DLAT = 1024;

// 0.125 (1/sqrt(64)) * log2(e): folded into Q so flash uses exp2 on raw MFMA output
#define QSCL 0.18033688011112042f

__device__ __forceinline__ u16 f2bf(float f){
  u32 u = __float_as_uint(f);
  u += 0x7FFFu + ((u >> 16) & 1u);
  return (u16)(u >> 16);
}
// pack two floats to 2 bf16 (truncation) in one v_perm
__device__ __forceinline__ u32 permpack(float hi, float lo){
  return __builtin_amdgcn_perm(__float_as_uint(hi), __float_as_uint(lo), 0x07060302u);
}

#define GLDS16(gp, lp) \
  __builtin_amdgcn_global_load_lds((const __attribute__((address_space(1))) u32*)(gp), \
                                   (__attribute__((address_space(3))) u32*)(lp), 16, 0, 0)

// ---------------- fused prep: rmsnorm + rope table + weight transposes ----------------
__device__ __forceinline__ void tc_body(
    const float* __restrict__ W, u16* __restrict__ Wt,
    int N, int ldt, int koff, int k0, int n0, float* tbuf)
{
  float (*t)[65] = (float(*)[65])tbuf;
  const int c = threadIdx.x & 63, r0 = threadIdx.x >> 6;
  #pragma unroll
  for (int i = 0; i < 16; ++i){
    int r = i*4 + r0;
    t[r][c] = W[(size_t)(k0 + r) * N + n0 + c];
  }
  __syncthreads();
  #pragma unroll
  for (int i = 0; i < 16; ++i){
    int r = i*4 + r0;
    Wt[(size_t)(n0 + r) * ldt + koff + k0 + c] = f2bf(t[c][r]);
  }
}

__global__ __launch_bounds__(256) void prep_kernel(
    const float* __restrict__ x, const float* __restrict__ norm_w,
    const float* __restrict__ wq_w, const float* __restrict__ wkv_w,
    const float* __restrict__ wout_w, const float* __restrict__ wbyp_w,
    u16* __restrict__ normb, u16* __restrict__ xb,
    float2* __restrict__ rtab,
    u16* __restrict__ wtq, u16* __restrict__ wtkv, u16* __restrict__ wto)
{
  __shared__ float tbuf[64*65];
  const int bid = blockIdx.x;
  if (bid < 2048){
    const int lane = threadIdx.x & 63;
    const int row  = bid * 4 + (threadIdx.x >> 6);
    const float4* xr = (const float4*)(x + (size_t)row * Dd);
    float4 a = xr[lane*2], b2 = xr[lane*2 + 1];
    float ss = a.x*a.x + a.y*a.y + a.z*a.z + a.w*a.w
             + b2.x*b2.x + b2.y*b2.y + b2.z*b2.z + b2.w*b2.w;
    #pragma unroll
    for (int off = 1; off < 64; off <<= 1) ss += __shfl_xor(ss, off);
    const float sc = rsqrtf(ss * (1.0f / Dd) + 1.1920929e-07f);
    const int c0 = lane * 8;
    const float4* wr4 = (const float4*)(norm_w + c0);
    float4 w0 = wr4[0], w1 = wr4[1];
    u16x8 nv, xv;
    nv[0]=f2bf(a.x *sc*w0.x); nv[1]=f2bf(a.y *sc*w0.y); nv[2]=f2bf(a.z *sc*w0.z); nv[3]=f2bf(a.w *sc*w0.w);
    nv[4]=f2bf(b2.x*sc*w1.x); nv[5]=f2bf(b2.y*sc*w1.y); nv[6]=f2bf(b2.z*sc*w1.z); nv[7]=f2bf(b2.w*sc*w1.w);
    xv[0]=f2bf(a.x);  xv[1]=f2bf(a.y);  xv[2]=f2bf(a.z);  xv[3]=f2bf(a.w);
    xv[4]=f2bf(b2.x); xv[5]=f2bf(b2.y); xv[6]=f2bf(b2.z); xv[7]=f2bf(b2.w);
    *(u16x8*)(normb + (size_t)row * Dd + c0) = nv;
    *(u16x8*)(xb    + (size_t)row * Dd + c0) = xv;
  } else if (bid < 2560){
    int i = (bid - 2048) * 256 + threadIdx.x;   // i < 4096*32
    int pos = i >> 5, d = i & 31;
    float inv = exp2f(-(float)d * 0.41524101186092028f);  // log2(10000)/32
    float ang = (float)pos * inv;
    float s, c;
    sincosf(ang, &s, &c);
    rtab[i] = make_float2(c, s);
  } else {
    int t = bid - 2560;
    if (t < 512){                         // wq: K=2048 x N=1024
      tc_body(wq_w, wtq, 1024, 2048, 0, (t & 31) * 64, (t >> 5) * 64, tbuf);
    } else if (t < 768){                  // wkv: K=512 x N=2048
      int u = t - 512;
      tc_body(wkv_w, wtkv, 2048, 512, 0, (u & 7) * 64, (u >> 3) * 64, tbuf);
    } else if (t < 1024){                 // wout -> wto koff 0
      int u = t - 768;
      tc_body(wout_w, wto, 1024, 3072, 0, (u & 15) * 64, (u >> 4) * 64, tbuf);
    } else {                              // wbyp -> wto koff 1024
      int u = t - 1024;
      tc_body(wbyp_w, wto, 1024, 3072, 1024, (u & 31) * 64, (u >> 5) * 64, tbuf);
    }
  }
}

// ---------------- GEMM core A: 64x64 tile, BK=64, 4 waves, k-split dual-A ----------------
__device__ __forceinline__ void gemm_core64(
    const u16* __restrict__ A, int lda, int ksplit,
    const u16* __restrict__ A2, int lda2,
    const u16* __restrict__ Bt, int ldb,
    int K, int bm0, int bn0, char* lds,
    f32x4 (&acc)[4])
{
  const int tid = threadIdx.x, lane = tid & 63, w = tid >> 6;
  const int l15 = lane & 15, l4 = lane >> 4;

  #pragma unroll
  for (int j = 0; j < 4; ++j) acc[j] = (f32x4){0.f, 0.f, 0.f, 0.f};

  auto stage = [&](int t){
    char* dst = lds + (t % 3) * 16384;
    const int k0 = t * 64;
    #pragma unroll
    for (int i = 0; i < 4; ++i){
      int u = i*256 + tid;
      int row = u >> 3;
      int colb = ((u & 7) * 16) ^ ((row & 7) << 4);
      const u16* src;
      if (row < 64){
        if (k0 < ksplit) src = A  + (size_t)(bm0 + row) * lda  + k0 + (colb >> 1);
        else             src = A2 + (size_t)(bm0 + row) * lda2 + (k0 - ksplit) + (colb >> 1);
      } else {
        src = Bt + (size_t)(bn0 + row - 64) * ldb + k0 + (colb >> 1);
      }
      GLDS16(src, dst + u*16);
    }
  };

  const int nt = K >> 6;
  stage(0);
  if (nt > 1) stage(1);

  #pragma unroll 1
  for (int t = 0; t < nt; ++t){
    if (t + 1 < nt) { asm volatile("s_waitcnt vmcnt(4)" ::: "memory"); }
    else            { asm volatile("s_waitcnt vmcnt(0)" ::: "memory"); }
    __builtin_amdgcn_s_barrier();
    __builtin_amdgcn_sched_barrier(0);          // keep reads below the barrier

    const char* kb = lds + (t % 3) * 16384;
    bf16x8 af[2], bf[4][2];
    #pragma unroll
    for (int ks = 0; ks < 2; ++ks){
      const int row = w*16 + l15;
      af[ks] = *(const bf16x8*)(kb + row*128 + ((ks*64 + l4*16) ^ ((row & 7) << 4)));
    }
    #pragma unroll
    for (int j = 0; j < 4; ++j)
      #pragma unroll
      for (int ks = 0; ks < 2; ++ks){
        const int row = 64 + j*16 + l15;
        bf[j][ks] = *(const bf16x8*)(kb + row*128 + ((ks*64 + l4*16) ^ ((row & 7) << 4)));
      }
    if (t + 2 < nt) stage(t + 2);               // different buffer: no hazard vs reads

    __builtin_amdgcn_s_setprio(1);
    #pragma unroll
    for (int ks = 0; ks < 2; ++ks)
      #pragma unroll
      for (int j = 0; j < 4; ++j)
        acc[j] = __builtin_amdgcn_mfma_f32_16x16x32_bf16(af[ks], bf[j][ks], acc[j], 0, 0, 0);
    __builtin_amdgcn_s_setprio(0);
  }
}

// ---------------- GEMM core B: 256x128 tile, BK=64, 8 waves (64x64 each), 512 threads --------
__device__ __forceinline__ void gemm_core256(
    const u16* __restrict__ A, int lda, int ksplit,
    const u16* __restrict__ A2, int lda2,
    const u16* __restrict__ Bt, int ldb,
    int K, int bm0, int bn0, char* lds,
    f32x4 (&acc)[4][4])
{
  const int tid = threadIdx.x, lane = tid & 63, w = tid >> 6;
  const int wr = w >> 1, wc = w & 1;
  const int l15 = lane & 15, l4 = lane >> 4;

  #pragma unroll
  for (int i = 0; i < 4; ++i)
    #pragma unroll
    for (int j = 0; j < 4; ++j) acc[i][j] = (f32x4){0.f, 0.f, 0.f, 0.f};

  auto stage = [&](int t){
    char* dst = lds + (t % 3) * 49152;
    const int k0 = t * 64;
    #pragma unroll
    for (int i = 0; i < 6; ++i){
      int u = i*512 + tid;                       // 0..3071 units of 16B
      int row = u >> 3;                          // 0..383
      int colb = ((u & 7) * 16) ^ ((row & 7) << 4);
      const u16* src;
      if (row < 256){
        if (k0 < ksplit) src = A  + (size_t)(bm0 + row) * lda  + k0 + (colb >> 1);
        else             src = A2 + (size_t)(bm0 + row) * lda2 + (k0 - ksplit) + (colb >> 1);
      } else {
        src = Bt + (size_t)(bn0 + row - 256) * ldb + k0 + (colb >> 1);
      }
      GLDS16(src, dst + u*16);
    }
  };

  const int nt = K >> 6;
  stage(0);
  if (nt > 1) stage(1);

  #pragma unroll 1
  for (int t = 0; t < nt; ++t){
    if (t + 1 < nt) { asm volatile("s_waitcnt vmcnt(6)" ::: "memory"); }
    else            { asm volatile("s_waitcnt vmcnt(0)" ::: "memory"); }
    __builtin_amdgcn_s_barrier();
    __builtin_amdgcn_sched_barrier(0);          // keep reads below the barrier

    const char* kb = lds + (t % 3) * 49152;
    bf16x8 af[4][2], bf[4][2];
    #pragma unroll
    for (int i = 0; i < 4; ++i)
      #pragma unroll
      for (int ks = 0; ks < 2; ++ks){
        const int row = wr*64 + i*16 + l15;
        af[i][ks] = *(const bf16x8*)(kb + row*128 + ((ks*64 + l4*16) ^ ((row & 7) << 4)));
      }
    #pragma unroll
    for (int j = 0; j < 4; ++j)
      #pragma unroll
      for (int ks = 0; ks < 2; ++ks){
        const int row = 256 + wc*64 + j*16 + l15;
        bf[j][ks] = *(const bf16x8*)(kb + row*128 + ((ks*64 + l4*16) ^ ((row & 7) << 4)));
      }
    if (t + 2 < nt) stage(t + 2);               // different buffer: no hazard vs reads

    __builtin_amdgcn_s_setprio(1);
    #pragma unroll
    for (int ks = 0; ks < 2; ++ks)
      #pragma unroll
      for (int i = 0; i < 4; ++i)
        #pragma unroll
        for (int j = 0; j < 4; ++j)
          acc[i][j] = __builtin_amdgcn_mfma_f32_16x16x32_bf16(af[i][ks], bf[j][ks], acc[i][j], 0, 0, 0);
    __builtin_amdgcn_s_setprio(0);
  }
}

// ---------------- fused Q-proj + KV-proj (256x128 tiles, 512 threads) ----------------
__global__ __launch_bounds__(512, 1) void qkv_kernel(
    const u16* __restrict__ normb,
    const u16* __restrict__ wtq, const u16* __restrict__ wtkv,
    const float* __restrict__ wq_b, const float* __restrict__ wkv_b,
    const float2* __restrict__ rtab,
    u16* __restrict__ Qb, u16* __restrict__ Kb, u16* __restrict__ Vtb)
{
  __shared__ char lds[147456];
  const int bid = blockIdx.x;
  const int lane = threadIdx.x & 63, w = threadIdx.x >> 6;
  const int wr = w >> 1, wc = w & 1;
  const int ml = (lane >> 4) * 4, nl = lane & 15;
  f32x4 acc[4][4];

  if (bid < 64){
    const int bm0 = (bid & 7) * 256, bn0 = (bid >> 3) * 128;
    gemm_core256(normb, 2048, 2048, normb, 2048, wtq, 2048, 2048, bm0, bn0, lds, acc);
    const int nbase = bn0 + wc*64;
    const int h = nbase >> 6;
    #pragma unroll
    for (int i = 0; i < 4; ++i){
      #pragma unroll
      for (int j = 0; j < 2; ++j){
        const int d1 = j*16 + nl;
        const float b1 = wq_b[nbase + j*16 + nl], b2v = wq_b[nbase + (j+2)*16 + nl];
        #pragma unroll
        for (int r = 0; r < 4; ++r){
          int m = bm0 + wr*64 + i*16 + ml + r;
          int b = m >> 10, lq = m & 1023;
          float x1 = acc[i][j][r] + b1;
          float x2 = acc[i][j+2][r] + b2v;
          float2 cs = rtab[(lq*4)*32 + d1];
          size_t ob = ((size_t)(b*Hh + h) * LQ + lq) * DQK;
          Qb[ob + d1]      = f2bf((x1*cs.x - x2*cs.y) * QSCL);
          Qb[ob + d1 + 32] = f2bf((x1*cs.y + x2*cs.x) * QSCL);
        }
      }
    }
  } else {
    const int t = bid - 64;
    const int bm0 = (t & 31) * 256, bn0 = (t >> 5) * 128;
    gemm_core256(normb, 512, 512, normb, 512, wtkv, 512, 512, bm0, bn0, lds, acc);
    const int nbase = bn0 + wc*64;
    const int kv = nbase >> 10;
    const int h = (nbase & 1023) >> 6;
    #pragma unroll
    for (int i = 0; i < 4; ++i){
      const int m0 = bm0 + wr*64 + i*16 + ml;
      const int b = m0 >> 12, s = m0 & 4095;
      if (kv == 0){
        #pragma unroll
        for (int r = 0; r < 4; ++r){
          size_t ob = ((size_t)(b*Hh + h) * Ss + s + r) * DQK;
          #pragma unroll
          for (int j = 0; j < 2; ++j){
            int d1 = j*16 + nl;
            float x1 = acc[i][j][r]   + wkv_b[nbase + j*16 + nl];
            float x2 = acc[i][j+2][r] + wkv_b[nbase + (j+2)*16 + nl];
            float2 cs = rtab[(s+r)*32 + d1];
            Kb[ob + d1]      = f2bf(x1*cs.x - x2*cs.y);
            Kb[ob + d1 + 32] = f2bf(x1*cs.y + x2*cs.x);
          }
        }
      } else {
        #pragma unroll
        for (int j = 0; j < 4; ++j){
          const int d = j*16 + nl;
          const float bb = wkv_b[nbase + d];
          uint2 pv;
          pv.x = permpack(acc[i][j][1] + bb, acc[i][j][0] + bb);
          pv.y = permpack(acc[i][j][3] + bb, acc[i][j][2] + bb);
          *(uint2*)(Vtb + (((size_t)(b*Hh + h)) * DQK + d) * Ss + s) = pv;
        }
      }
    }
  }
}

// ---------------- OUT: single k-split pass (K=1024 attn + 2048 bypass), fp32 out ----------------
__global__ __launch_bounds__(256, 3) void out_kernel(
    const u16* __restrict__ ACb, const u16* __restrict__ xb,
    const u16* __restrict__ wto, const float* __restrict__ wout_b,
    float* __restrict__ outp)
{
  __shared__ char lds[49152];
  const int bm0 = blockIdx.x * 64, bn0 = blockIdx.y * 64;
  const int lane = threadIdx.x & 63, w = threadIdx.x >> 6;
  const int ml = (lane >> 4) * 4, nl = lane & 15;
  f32x4 acc[4];
  gemm_core64(ACb, 1024, 1024, xb, 2048, wto, 3072, 3072, bm0, bn0, lds, acc);
  #pragma unroll
  for (int j = 0; j < 4; ++j){
    const int n = bn0 + j*16 + nl;
    const float bb = wout_b[n];
    #pragma unroll
    for (int r = 0; r < 4; ++r){
      int m = bm0 + w*16 + ml + r;
      outp[(size_t)m * DLAT + n] = acc[j][r] + bb;
    }
  }
}

// ---------------- flash attention: 512 blocks x 4 waves (2 barrier domains/CU) ----------------
// R16: R13-done-right — 2 independent blocks per CU at the SAME 16 iterations/block
// (R13 halved iters, confounding TLP with prologue overhead). Per-wave geometry
// identical to R12-R15 (64 q/wave, 64 kv/iter, shared-KV LDS stream, 3-buf
// counted-vmcnt distance-2). Blocks: 32 bh x 4 q-quads(256q) x 4 S-quarters.
__global__ __launch_bounds__(256, 2) void flash_kernel(
    const u16* __restrict__ Qg, const u16* __restrict__ Kg,
    const u16* __restrict__ Vtg, u16* __restrict__ Opart,
    float* __restrict__ lpart)
{
  const int tid = threadIdx.x, lane = tid & 63, w = tid >> 6;
  const int bid = blockIdx.x;
  const int swz = (bid & 7) * 64 + (bid >> 3);     // XCD-chunked over 512 blocks
  const int sq = swz & 3, qq = (swz >> 2) & 3, bh = swz >> 4;
  const int sbase = sq * 1024;                     // S-quarter
  const int l31 = lane & 31, hgl = lane >> 5;

  __shared__ char lds[49152];                      // 3 bufs x (K 8KB | V 8KB)

  bf16x8 qf[2][4];
  #pragma unroll
  for (int qt = 0; qt < 2; ++qt)
    #pragma unroll
    for (int ks = 0; ks < 4; ++ks)
      qf[qt][ks] = *(const bf16x8*)(Qg + ((size_t)bh*LQ + qq*256 + w*64 + qt*32 + l31) * DQK + ks*16 + hgl*8);

  f32x16 o[2][2];
  #pragma unroll
  for (int qt = 0; qt < 2; ++qt)
    #pragma unroll
    for (int nd = 0; nd < 2; ++nd)
      #pragma unroll
      for (int r = 0; r < 16; ++r) o[qt][nd][r] = 0.f;
  float l_run[2] = {0.f, 0.f};

  auto stage = [&](int t){                         // 4 waves: 4 GLDS each
    char* dst = lds + (t % 3) * 16384;
    const int s0 = sbase + t * 64;
    #pragma unroll
    for (int i = 0; i < 4; ++i){
      int u = (w*4 + i) * 64 + lane;               // 0..1023 units of 16B
      int row = (u >> 3) & 63;
      int colb = ((u & 7) * 16) ^ ((row & 7) << 4);
      const u16* src = (u < 512)
          ? Kg  + ((size_t)bh*Ss  + s0 + row) * DQK + (colb >> 1)
          : Vtg + ((size_t)bh*DQK + row) * Ss + s0  + (colb >> 1);
      GLDS16(src, dst + u*16);
    }
  };

  stage(0);
  stage(1);

  #pragma unroll 1
  for (int t = 0; t < 16; ++t){
    if (t < 15) { asm volatile("s_waitcnt vmcnt(4)" ::: "memory"); }   // stage(t) done
    else        { asm volatile("s_waitcnt vmcnt(0)" ::: "memory"); }
    __builtin_amdgcn_s_barrier();
    __builtin_amdgcn_sched_barrier(0);             // keep reads below the barrier

    const char* kb = lds + (t % 3) * 16384;
    bf16x8 kf[2][4];
    #pragma unroll
    for (int kvt = 0; kvt < 2; ++kvt)
      #pragma unroll
      for (int ks = 0; ks < 4; ++ks){
        const int row = kvt*32 + l31;
        kf[kvt][ks] = *(const bf16x8*)(kb + row*128 + ((ks*32 + hgl*16) ^ ((row & 7) << 4)));
      }
    if (t < 14) stage(t + 2);                      // different buffer: no hazard vs reads

    // QK for BOTH q-tiles; V reads + softmax VALU free to interleave under MFMAs
    f32x16 sc[2][2];
    #pragma unroll
    for (int qt = 0; qt < 2; ++qt)
      #pragma unroll
      for (int kvt = 0; kvt < 2; ++kvt)
        #pragma unroll
        for (int r = 0; r < 16; ++r) sc[qt][kvt][r] = 0.f;
    __builtin_amdgcn_s_setprio(1);
    #pragma unroll
    for (int qt = 0; qt < 2; ++qt)
      #pragma unroll
      for (int kvt = 0; kvt < 2; ++kvt)
        #pragma unroll
        for (int ks = 0; ks < 4; ++ks)
          sc[qt][kvt] = __builtin_amdgcn_mfma_f32_32x32x16_bf16(kf[kvt][ks], qf[qt][ks], sc[qt][kvt], 0, 0, 0);
    __builtin_amdgcn_s_setprio(0);

    bf16x8 vf[2][4];
    #pragma unroll
    for (int nd = 0; nd < 2; ++nd)
      #pragma unroll
      for (int k2 = 0; k2 < 4; ++k2){
        const int row = nd*32 + l31;
        vf[nd][k2] = *(const bf16x8*)(kb + 8192 + row*128 + ((k2*32 + hgl*16) ^ ((row & 7) << 4)));
      }

    // SM0 -> PV0 -> SM1 (VALU overlaps PV0's MFMAs) -> PV1
    #pragma unroll
    for (int qt = 0; qt < 2; ++qt){
      #pragma unroll
      for (int kvt = 0; kvt < 2; ++kvt)
        #pragma unroll
        for (int r = 0; r < 16; ++r)
          sc[qt][kvt][r] = __builtin_amdgcn_exp2f(sc[qt][kvt][r]);
      f32x16 es = sc[qt][0] + sc[qt][1];
      float a0 = es[0]+es[8],  a1 = es[1]+es[9],  a2 = es[2]+es[10], a3 = es[3]+es[11];
      float a4 = es[4]+es[12], a5 = es[5]+es[13], a6 = es[6]+es[14], a7 = es[7]+es[15];
      float b0 = a0+a4, b1 = a1+a5, b2 = a2+a6, b3 = a3+a7;
      l_run[qt] += (b0+b1) + (b2+b3);

      u32x4 paw[4];
      #pragma unroll
      for (int kvt = 0; kvt < 2; ++kvt)
        #pragma unroll
        for (int k2r = 0; k2r < 2; ++k2r){
          u32 w0 = permpack(sc[qt][kvt][k2r*8+1], sc[qt][kvt][k2r*8+0]);
          u32 w1 = permpack(sc[qt][kvt][k2r*8+3], sc[qt][kvt][k2r*8+2]);
          u32 w2 = permpack(sc[qt][kvt][k2r*8+5], sc[qt][kvt][k2r*8+4]);
          u32 w3 = permpack(sc[qt][kvt][k2r*8+7], sc[qt][kvt][k2r*8+6]);
          asm("v_permlane32_swap_b32 %0, %1" : "+v"(w0), "+v"(w2));
          asm("v_permlane32_swap_b32 %0, %1" : "+v"(w1), "+v"(w3));
          const int k2 = kvt*2 + k2r;
          paw[k2][0] = w0; paw[k2][1] = w1;
          paw[k2][2] = w2; paw[k2][3] = w3;
        }

      __builtin_amdgcn_s_setprio(1);
      #pragma unroll
      for (int nd = 0; nd < 2; ++nd)
        #pragma unroll
        for (int k2 = 0; k2 < 4; ++k2)
          o[qt][nd] = __builtin_amdgcn_mfma_f32_32x32x16_bf16(
              __builtin_bit_cast(bf16x8, paw[k2]), vf[nd][k2], o[qt][nd], 0, 0, 0);
      __builtin_amdgcn_s_setprio(0);
    }
  }

  // ---- write bf16 partial (O, l) for this S-quarter ----
  #pragma unroll
  for (int qt = 0; qt < 2; ++qt){
    float lf = l_run[qt] + __shfl_xor(l_run[qt], 32);
    u16* Ob = Opart + ((size_t)sq * 32768 + (size_t)bh * 1024) * 64;
    #pragma unroll
    for (int nd = 0; nd < 2; ++nd)
      #pragma unroll
      for (int r = 0; r < 16; ++r){
        int q = qq*256 + w*64 + qt*32 + (r & 3) + 8*(r >> 2) + 4*hgl;
        Ob[(size_t)q * 64 + nd*32 + l31] = f2bf(o[qt][nd][r]);
      }
    if (hgl == 0)
      lpart[(size_t)sq * 32768 + (size_t)bh * 1024 + qq*256 + w*64 + qt*32 + l31] = lf;
  }
}

// ---------------- merge the 4 S-quarter partials -> AC bf16 ----------------
__global__ __launch_bounds__(256) void merge_kernel(
    const u16* __restrict__ Opart, const float* __restrict__ lpart,
    u16* __restrict__ AC)
{
  int idx = blockIdx.x * 256 + threadIdx.x;       // 262144 = 32768 rows x 8 dgroups
  int row = idx >> 3, dg = idx & 7;
  int bh = row >> 10, lq = row & 1023;
  int b = bh >> 4, h = bh & 15;
  float a[8];
  #pragma unroll
  for (int e = 0; e < 8; ++e) a[e] = 0.f;
  float lt = 0.f;
  #pragma unroll
  for (int p = 0; p < 4; ++p){
    u16x8 v = *(const u16x8*)(Opart + ((size_t)p * 32768 + row) * 64 + dg * 8);
    #pragma unroll
    for (int e = 0; e < 8; ++e)
      a[e] += __uint_as_float((u32)v[e] << 16);
    lt += lpart[(size_t)p * 32768 + row];
  }
  float rl = 1.0f / lt;
  u16x8 r;
  #pragma unroll
  for (int e = 0; e < 8; ++e) r[e] = f2bf(a[e] * rl);
  *(u16x8*)(AC + ((size_t)(b*LQ + lq)) * (Hh*DQK) + h*DQK + dg*8) = r;
}

// ---------------- host ----------------
extern "C" void kernel_launch(void* const* d_in, const int* in_sizes, int n_in,
                              void* d_out, int out_size, void* d_ws, size_t ws_size,
                              hipStream_t stream)
{
  (void)in_sizes; (void)n_in; (void)out_size; (void)ws_size;
  const float* x      = (const float*)d_in[0];
  const float* norm_w = (const float*)d_in[1];
  const float* wq_w   = (const float*)d_in[2];
  const float* wq_b   = (const float*)d_in[3];
  const float* wkv_w  = (const float*)d_in[4];
  const float* wkv_b  = (const float*)d_in[5];
  const float* wout_w = (const float*)d_in[6];
  const float* wout_b = (const float*)d_in[7];
  const float* wbyp_w = (const float*)d_in[8];
  float* outp = (float*)d_out;

  char* p = (char*)d_ws;
  u16* normb = (u16*)p; p += (size_t)8192*512*2;     // norm bf16 (B*S, D)
  u16* xb    = (u16*)p; p += (size_t)8192*512*2;     // x bf16
  u16* wtq   = (u16*)p; p += (size_t)1024*2048*2;    // wq^T  (N=1024, K=2048)
  u16* wtkv  = (u16*)p; p += (size_t)2048*512*2;     // wkv^T (N=2048, K=512)
  u16* wto   = (u16*)p; p += (size_t)1024*3072*2;    // [wout;wbyp]^T (N=1024, K=3072)
  u16* Qb    = (u16*)p; p += (size_t)32*1024*64*2;   // Q  (B,H, LQ, 64), pre-scaled
  u16* Kb    = (u16*)p; p += (size_t)32*4096*64*2;   // K  (B,H, S, 64)
  u16* Vtb   = (u16*)p; p += (size_t)32*64*4096*2;   // V^T (B,H, 64, S)
  u16* ACb   = (u16*)p; p += (size_t)2048*1024*2;    // attn_concat bf16
  float2* rtab = (float2*)p; p += (size_t)4096*32*sizeof(float2);
  u16* Opart = (u16*)p; p += (size_t)4*32768*64*2;   // [sq][bh][1024][64] bf16
  float* lpart = (float*)p; p += (size_t)4*32768*4;  // [sq][bh][1024]

  prep_kernel<<<4096, 256, 0, stream>>>(x, norm_w, wq_w, wkv_w, wout_w, wbyp_w,
                                        normb, xb, rtab, wtq, wtkv, wto);
  // fused Q-proj (64 blocks) + KV-proj (512 blocks), 256x128 tiles, 512 threads
  qkv_kernel<<<576, 512, 0, stream>>>(normb, wtq, wtkv, wq_b, wkv_b, rtab, Qb, Kb, Vtb);
  flash_kernel<<<512, 256, 0, stream>>>(Qb, Kb, Vtb, Opart, lpart);
  merge_kernel<<<1024, 256, 0, stream>>>(Opart, lpart, ACb);
  // OUT: M=2048, N=1024, K=3072 single k-split pass
  out_kernel<<<dim3(32,16), 256, 0, stream>>>(ACb, xb, wto, wout_b, outp);
}

// Round 17
// 119.746 us; speedup vs baseline: 1.0126x; 1.0126x over previous
//
#include <hip/hip_runtime.h>

using u16 = unsigned short;
using u32 = unsigned int;

typedef __attribute__((ext_vector_type(8))) short bf16x8;
typedef __attribute__((ext_vector_type(8))) unsigned short u16x8;
typedef __attribute__((ext_vector_type(4))) float f32x4;
typedef __attribute__((ext_vector_type(16))) float f32x16;
typedef __attribute__((ext_vector_type(4))) u32 u32x4;

constexpr int Bb   = 2;
constexpr int Ss   = 4096;
constexpr int Dd   = 512;
constexpr int Hh   = 16;
constexpr int DQK  = 64;
constexpr int LQ   = 1024;   // S / BPL
constexpr int DLAT = 1024;

// 0.125 (1/sqrt(64)) * log2(e): folded into Q so flash uses exp2 on raw MFMA output
#define QSCL 0.18033688011112042f

__device__ __forceinline__ u16 f2bf(float f){
  u32 u = __float_as_uint(f);
  u += 0x7FFFu + ((u >> 16) & 1u);
  return (u16)(u >> 16);
}
// pack two floats to 2 bf16 (truncation) in one v_perm
__device__ __forceinline__ u32 permpack(float hi, float lo){
  return __builtin_amdgcn_perm(__float_as_uint(hi), __float_as_uint(lo), 0x07060302u);
}

#define GLDS16(gp, lp) \
  __builtin_amdgcn_global_load_lds((const __attribute__((address_space(1))) u32*)(gp), \
                                   (__attribute__((address_space(3))) u32*)(lp), 16, 0, 0)

// ---------------- fused prep: rmsnorm + rope table + weight transposes ----------------
__device__ __forceinline__ void tc_body(
    const float* __restrict__ W, u16* __restrict__ Wt,
    int N, int ldt, int koff, int k0, int n0, float* tbuf)
{
  float (*t)[65] = (float(*)[65])tbuf;
  const int c = threadIdx.x & 63, r0 = threadIdx.x >> 6;
  #pragma unroll
  for (int i = 0; i < 16; ++i){
    int r = i*4 + r0;
    t[r][c] = W[(size_t)(k0 + r) * N + n0 + c];
  }
  __syncthreads();
  #pragma unroll
  for (int i = 0; i < 16; ++i){
    int r = i*4 + r0;
    Wt[(size_t)(n0 + r) * ldt + koff + k0 + c] = f2bf(t[c][r]);
  }
}

__global__ __launch_bounds__(256) void prep_kernel(
    const float* __restrict__ x, const float* __restrict__ norm_w,
    const float* __restrict__ wq_w, const float* __restrict__ wkv_w,
    const float* __restrict__ wout_w, const float* __restrict__ wbyp_w,
    u16* __restrict__ normb, u16* __restrict__ xb,
    float2* __restrict__ rtab,
    u16* __restrict__ wtq, u16* __restrict__ wtkv, u16* __restrict__ wto)
{
  __shared__ float tbuf[64*65];
  const int bid = blockIdx.x;
  if (bid < 2048){
    const int lane = threadIdx.x & 63;
    const int row  = bid * 4 + (threadIdx.x >> 6);
    const float4* xr = (const float4*)(x + (size_t)row * Dd);
    float4 a = xr[lane*2], b2 = xr[lane*2 + 1];
    float ss = a.x*a.x + a.y*a.y + a.z*a.z + a.w*a.w
             + b2.x*b2.x + b2.y*b2.y + b2.z*b2.z + b2.w*b2.w;
    #pragma unroll
    for (int off = 1; off < 64; off <<= 1) ss += __shfl_xor(ss, off);
    const float sc = rsqrtf(ss * (1.0f / Dd) + 1.1920929e-07f);
    const int c0 = lane * 8;
    const float4* wr4 = (const float4*)(norm_w + c0);
    float4 w0 = wr4[0], w1 = wr4[1];
    u16x8 nv, xv;
    nv[0]=f2bf(a.x *sc*w0.x); nv[1]=f2bf(a.y *sc*w0.y); nv[2]=f2bf(a.z *sc*w0.z); nv[3]=f2bf(a.w *sc*w0.w);
    nv[4]=f2bf(b2.x*sc*w1.x); nv[5]=f2bf(b2.y*sc*w1.y); nv[6]=f2bf(b2.z*sc*w1.z); nv[7]=f2bf(b2.w*sc*w1.w);
    xv[0]=f2bf(a.x);  xv[1]=f2bf(a.y);  xv[2]=f2bf(a.z);  xv[3]=f2bf(a.w);
    xv[4]=f2bf(b2.x); xv[5]=f2bf(b2.y); xv[6]=f2bf(b2.z); xv[7]=f2bf(b2.w);
    *(u16x8*)(normb + (size_t)row * Dd + c0) = nv;
    *(u16x8*)(xb    + (size_t)row * Dd + c0) = xv;
  } else if (bid < 2560){
    int i = (bid - 2048) * 256 + threadIdx.x;   // i < 4096*32
    int pos = i >> 5, d = i & 31;
    float inv = exp2f(-(float)d * 0.41524101186092028f);  // log2(10000)/32
    float ang = (float)pos * inv;
    float s, c;
    sincosf(ang, &s, &c);
    rtab[i] = make_float2(c, s);
  } else {
    int t = bid - 2560;
    if (t < 512){                         // wq: K=2048 x N=1024
      tc_body(wq_w, wtq, 1024, 2048, 0, (t & 31) * 64, (t >> 5) * 64, tbuf);
    } else if (t < 768){                  // wkv: K=512 x N=2048
      int u = t - 512;
      tc_body(wkv_w, wtkv, 2048, 512, 0, (u & 7) * 64, (u >> 3) * 64, tbuf);
    } else if (t < 1024){                 // wout -> wto koff 0
      int u = t - 768;
      tc_body(wout_w, wto, 1024, 3072, 0, (u & 15) * 64, (u >> 4) * 64, tbuf);
    } else {                              // wbyp -> wto koff 1024
      int u = t - 1024;
      tc_body(wbyp_w, wto, 1024, 3072, 1024, (u & 31) * 64, (u >> 5) * 64, tbuf);
    }
  }
}

// ---------------- GEMM core A: 64x64 tile, BK=64, 4 waves, k-split dual-A ----------------
__device__ __forceinline__ void gemm_core64(
    const u16* __restrict__ A, int lda, int ksplit,
    const u16* __restrict__ A2, int lda2,
    const u16* __restrict__ Bt, int ldb,
    int K, int bm0, int bn0, char* lds,
    f32x4 (&acc)[4])
{
  const int tid = threadIdx.x, lane = tid & 63, w = tid >> 6;
  const int l15 = lane & 15, l4 = lane >> 4;

  #pragma unroll
  for (int j = 0; j < 4; ++j) acc[j] = (f32x4){0.f, 0.f, 0.f, 0.f};

  auto stage = [&](int t){
    char* dst = lds + (t % 3) * 16384;
    const int k0 = t * 64;
    #pragma unroll
    for (int i = 0; i < 4; ++i){
      int u = i*256 + tid;
      int row = u >> 3;
      int colb = ((u & 7) * 16) ^ ((row & 7) << 4);
      const u16* src;
      if (row < 64){
        if (k0 < ksplit) src = A  + (size_t)(bm0 + row) * lda  + k0 + (colb >> 1);
        else             src = A2 + (size_t)(bm0 + row) * lda2 + (k0 - ksplit) + (colb >> 1);
      } else {
        src = Bt + (size_t)(bn0 + row - 64) * ldb + k0 + (colb >> 1);
      }
      GLDS16(src, dst + u*16);
    }
  };

  const int nt = K >> 6;
  stage(0);
  if (nt > 1) stage(1);

  #pragma unroll 1
  for (int t = 0; t < nt; ++t){
    if (t + 1 < nt) { asm volatile("s_waitcnt vmcnt(4)" ::: "memory"); }
    else            { asm volatile("s_waitcnt vmcnt(0)" ::: "memory"); }
    __builtin_amdgcn_s_barrier();
    __builtin_amdgcn_sched_barrier(0);          // keep reads below the barrier

    const char* kb = lds + (t % 3) * 16384;
    bf16x8 af[2], bf[4][2];
    #pragma unroll
    for (int ks = 0; ks < 2; ++ks){
      const int row = w*16 + l15;
      af[ks] = *(const bf16x8*)(kb + row*128 + ((ks*64 + l4*16) ^ ((row & 7) << 4)));
    }
    #pragma unroll
    for (int j = 0; j < 4; ++j)
      #pragma unroll
      for (int ks = 0; ks < 2; ++ks){
        const int row = 64 + j*16 + l15;
        bf[j][ks] = *(const bf16x8*)(kb + row*128 + ((ks*64 + l4*16) ^ ((row & 7) << 4)));
      }
    if (t + 2 < nt) stage(t + 2);               // different buffer: no hazard vs reads

    #pragma unroll
    for (int ks = 0; ks < 2; ++ks)
      #pragma unroll
      for (int j = 0; j < 4; ++j)
        acc[j] = __builtin_amdgcn_mfma_f32_16x16x32_bf16(af[ks], bf[j][ks], acc[j], 0, 0, 0);
  }
}

// ---------------- GEMM core B: 256x128 tile, BK=64, 8 waves (64x64 each), 512 threads --------
__device__ __forceinline__ void gemm_core256(
    const u16* __restrict__ A, int lda, int ksplit,
    const u16* __restrict__ A2, int lda2,
    const u16* __restrict__ Bt, int ldb,
    int K, int bm0, int bn0, char* lds,
    f32x4 (&acc)[4][4])
{
  const int tid = threadIdx.x, lane = tid & 63, w = tid >> 6;
  const int wr = w >> 1, wc = w & 1;
  const int l15 = lane & 15, l4 = lane >> 4;

  #pragma unroll
  for (int i = 0; i < 4; ++i)
    #pragma unroll
    for (int j = 0; j < 4; ++j) acc[i][j] = (f32x4){0.f, 0.f, 0.f, 0.f};

  auto stage = [&](int t){
    char* dst = lds + (t % 3) * 49152;
    const int k0 = t * 64;
    #pragma unroll
    for (int i = 0; i < 6; ++i){
      int u = i*512 + tid;                       // 0..3071 units of 16B
      int row = u >> 3;                          // 0..383
      int colb = ((u & 7) * 16) ^ ((row & 7) << 4);
      const u16* src;
      if (row < 256){
        if (k0 < ksplit) src = A  + (size_t)(bm0 + row) * lda  + k0 + (colb >> 1);
        else             src = A2 + (size_t)(bm0 + row) * lda2 + (k0 - ksplit) + (colb >> 1);
      } else {
        src = Bt + (size_t)(bn0 + row - 256) * ldb + k0 + (colb >> 1);
      }
      GLDS16(src, dst + u*16);
    }
  };

  const int nt = K >> 6;
  stage(0);
  if (nt > 1) stage(1);

  #pragma unroll 1
  for (int t = 0; t < nt; ++t){
    if (t + 1 < nt) { asm volatile("s_waitcnt vmcnt(6)" ::: "memory"); }
    else            { asm volatile("s_waitcnt vmcnt(0)" ::: "memory"); }
    __builtin_amdgcn_s_barrier();
    __builtin_amdgcn_sched_barrier(0);          // keep reads below the barrier

    const char* kb = lds + (t % 3) * 49152;
    bf16x8 af[4][2], bf[4][2];
    #pragma unroll
    for (int i = 0; i < 4; ++i)
      #pragma unroll
      for (int ks = 0; ks < 2; ++ks){
        const int row = wr*64 + i*16 + l15;
        af[i][ks] = *(const bf16x8*)(kb + row*128 + ((ks*64 + l4*16) ^ ((row & 7) << 4)));
      }
    #pragma unroll
    for (int j = 0; j < 4; ++j)
      #pragma unroll
      for (int ks = 0; ks < 2; ++ks){
        const int row = 256 + wc*64 + j*16 + l15;
        bf[j][ks] = *(const bf16x8*)(kb + row*128 + ((ks*64 + l4*16) ^ ((row & 7) << 4)));
      }
    if (t + 2 < nt) stage(t + 2);               // different buffer: no hazard vs reads

    #pragma unroll
    for (int ks = 0; ks < 2; ++ks)
      #pragma unroll
      for (int i = 0; i < 4; ++i)
        #pragma unroll
        for (int j = 0; j < 4; ++j)
          acc[i][j] = __builtin_amdgcn_mfma_f32_16x16x32_bf16(af[i][ks], bf[j][ks], acc[i][j], 0, 0, 0);
  }
}

// ---------------- fused Q-proj + KV-proj (256x128 tiles, 512 threads) ----------------
__global__ __launch_bounds__(512, 1) void qkv_kernel(
    const u16* __restrict__ normb,
    const u16* __restrict__ wtq, const u16* __restrict__ wtkv,
    const float* __restrict__ wq_b, const float* __restrict__ wkv_b,
    const float2* __restrict__ rtab,
    u16* __restrict__ Qb, u16* __restrict__ Kb, u16* __restrict__ Vtb)
{
  __shared__ char lds[147456];
  const int bid = blockIdx.x;
  const int lane = threadIdx.x & 63, w = threadIdx.x >> 6;
  const int wr = w >> 1, wc = w & 1;
  const int ml = (lane >> 4) * 4, nl = lane & 15;
  f32x4 acc[4][4];

  if (bid < 64){
    const int bm0 = (bid & 7) * 256, bn0 = (bid >> 3) * 128;
    gemm_core256(normb, 2048, 2048, normb, 2048, wtq, 2048, 2048, bm0, bn0, lds, acc);
    const int nbase = bn0 + wc*64;
    const int h = nbase >> 6;
    #pragma unroll
    for (int i = 0; i < 4; ++i){
      #pragma unroll
      for (int j = 0; j < 2; ++j){
        const int d1 = j*16 + nl;
        const float b1 = wq_b[nbase + j*16 + nl], b2v = wq_b[nbase + (j+2)*16 + nl];
        #pragma unroll
        for (int r = 0; r < 4; ++r){
          int m = bm0 + wr*64 + i*16 + ml + r;
          int b = m >> 10, lq = m & 1023;
          float x1 = acc[i][j][r] + b1;
          float x2 = acc[i][j+2][r] + b2v;
          float2 cs = rtab[(lq*4)*32 + d1];
          size_t ob = ((size_t)(b*Hh + h) * LQ + lq) * DQK;
          Qb[ob + d1]      = f2bf((x1*cs.x - x2*cs.y) * QSCL);
          Qb[ob + d1 + 32] = f2bf((x1*cs.y + x2*cs.x) * QSCL);
        }
      }
    }
  } else {
    const int t = bid - 64;
    const int bm0 = (t & 31) * 256, bn0 = (t >> 5) * 128;
    gemm_core256(normb, 512, 512, normb, 512, wtkv, 512, 512, bm0, bn0, lds, acc);
    const int nbase = bn0 + wc*64;
    const int kv = nbase >> 10;
    const int h = (nbase & 1023) >> 6;
    #pragma unroll
    for (int i = 0; i < 4; ++i){
      const int m0 = bm0 + wr*64 + i*16 + ml;
      const int b = m0 >> 12, s = m0 & 4095;
      if (kv == 0){
        #pragma unroll
        for (int r = 0; r < 4; ++r){
          size_t ob = ((size_t)(b*Hh + h) * Ss + s + r) * DQK;
          #pragma unroll
          for (int j = 0; j < 2; ++j){
            int d1 = j*16 + nl;
            float x1 = acc[i][j][r]   + wkv_b[nbase + j*16 + nl];
            float x2 = acc[i][j+2][r] + wkv_b[nbase + (j+2)*16 + nl];
            float2 cs = rtab[(s+r)*32 + d1];
            Kb[ob + d1]      = f2bf(x1*cs.x - x2*cs.y);
            Kb[ob + d1 + 32] = f2bf(x1*cs.y + x2*cs.x);
          }
        }
      } else {
        #pragma unroll
        for (int j = 0; j < 4; ++j){
          const int d = j*16 + nl;
          const float bb = wkv_b[nbase + d];
          uint2 pv;
          pv.x = permpack(acc[i][j][1] + bb, acc[i][j][0] + bb);
          pv.y = permpack(acc[i][j][3] + bb, acc[i][j][2] + bb);
          *(uint2*)(Vtb + (((size_t)(b*Hh + h)) * DQK + d) * Ss + s) = pv;
        }
      }
    }
  }
}

// ---------------- OUT: single k-split pass (K=1024 attn + 2048 bypass), fp32 out ----------------
__global__ __launch_bounds__(256, 3) void out_kernel(
    const u16* __restrict__ ACb, const u16* __restrict__ xb,
    const u16* __restrict__ wto, const float* __restrict__ wout_b,
    float* __restrict__ outp)
{
  __shared__ char lds[49152];
  const int bm0 = blockIdx.x * 64, bn0 = blockIdx.y * 64;
  const int lane = threadIdx.x & 63, w = threadIdx.x >> 6;
  const int ml = (lane >> 4) * 4, nl = lane & 15;
  f32x4 acc[4];
  gemm_core64(ACb, 1024, 1024, xb, 2048, wto, 3072, 3072, bm0, bn0, lds, acc);
  #pragma unroll
  for (int j = 0; j < 4; ++j){
    const int n = bn0 + j*16 + nl;
    const float bb = wout_b[n];
    #pragma unroll
    for (int r = 0; r < 4; ++r){
      int m = bm0 + w*16 + ml + r;
      outp[(size_t)m * DLAT + n] = acc[j][r] + bb;
    }
  }
}

// ---------------- flash attention: R14-exact structure (best measured), no setprio --------
// 256 blocks (1/CU), 8 waves, 16 iters. Shared-KV LDS stream, 3-buf counted-vmcnt
// distance-2, lgkm walls (R14 variant, 44.0us). setprio removed: 8-wave lockstep
// structure -> setprio null-to-negative (m190).
__global__ __launch_bounds__(512, 2) void flash_kernel(
    const u16* __restrict__ Qg, const u16* __restrict__ Kg,
    const u16* __restrict__ Vtg, u16* __restrict__ Opart,
    float* __restrict__ lpart)
{
  const int tid = threadIdx.x, lane = tid & 63, w = tid >> 6;
  const int bid = blockIdx.x;
  const int swz = (bid & 7) * 32 + (bid >> 3);     // XCD-chunked over 256 blocks
  const int sq = swz & 3, qh = (swz >> 2) & 1, bh = swz >> 3;
  const int sbase = sq * 1024;                     // S-quarter
  const int l31 = lane & 31, hgl = lane >> 5;

  __shared__ char lds[49152];                      // 3 bufs x (K 8KB | V 8KB)

  bf16x8 qf[2][4];
  #pragma unroll
  for (int qt = 0; qt < 2; ++qt)
    #pragma unroll
    for (int ks = 0; ks < 4; ++ks)
      qf[qt][ks] = *(const bf16x8*)(Qg + ((size_t)bh*LQ + qh*512 + w*64 + qt*32 + l31) * DQK + ks*16 + hgl*8);

  f32x16 o[2][2];
  #pragma unroll
  for (int qt = 0; qt < 2; ++qt)
    #pragma unroll
    for (int nd = 0; nd < 2; ++nd)
      #pragma unroll
      for (int r = 0; r < 16; ++r) o[qt][nd][r] = 0.f;
  float l_run[2] = {0.f, 0.f};

  auto stage = [&](int t){                         // all 8 waves: 2 GLDS each
    char* dst = lds + (t % 3) * 16384;
    const int s0 = sbase + t * 64;
    #pragma unroll
    for (int i = 0; i < 2; ++i){
      int u = (w*2 + i) * 64 + lane;               // 0..1023 units of 16B
      int row = (u >> 3) & 63;
      int colb = ((u & 7) * 16) ^ ((row & 7) << 4);
      const u16* src = (u < 512)
          ? Kg  + ((size_t)bh*Ss  + s0 + row) * DQK + (colb >> 1)
          : Vtg + ((size_t)bh*DQK + row) * Ss + s0  + (colb >> 1);
      GLDS16(src, dst + u*16);
    }
  };

  stage(0);
  stage(1);

  #pragma unroll 1
  for (int t = 0; t < 16; ++t){
    if (t < 15) { asm volatile("s_waitcnt vmcnt(2)" ::: "memory"); }   // stage(t) done
    else        { asm volatile("s_waitcnt vmcnt(0)" ::: "memory"); }
    __builtin_amdgcn_sched_barrier(0);
    __builtin_amdgcn_s_barrier();

    const char* kb = lds + (t % 3) * 16384;
    bf16x8 kf[2][4];
    #pragma unroll
    for (int kvt = 0; kvt < 2; ++kvt)
      #pragma unroll
      for (int ks = 0; ks < 4; ++ks){
        const int row = kvt*32 + l31;
        kf[kvt][ks] = *(const bf16x8*)(kb + row*128 + ((ks*32 + hgl*16) ^ ((row & 7) << 4)));
      }
    asm volatile("s_waitcnt lgkmcnt(0)" ::: "memory");
    __builtin_amdgcn_sched_barrier(0);
    if (t < 14) stage(t + 2);                      // buf[(t+2)%3] freed by barrier

    // --- QK for BOTH q-tiles (32 MFMA issued back-to-back) ---
    f32x16 sc[2][2];
    #pragma unroll
    for (int qt = 0; qt < 2; ++qt)
      #pragma unroll
      for (int kvt = 0; kvt < 2; ++kvt)
        #pragma unroll
        for (int r = 0; r < 16; ++r) sc[qt][kvt][r] = 0.f;
    #pragma unroll
    for (int qt = 0; qt < 2; ++qt)
      #pragma unroll
      for (int kvt = 0; kvt < 2; ++kvt)
        #pragma unroll
        for (int ks = 0; ks < 4; ++ks)
          sc[qt][kvt] = __builtin_amdgcn_mfma_f32_32x32x16_bf16(kf[kvt][ks], qf[qt][ks], sc[qt][kvt], 0, 0, 0);

    // V fragments (LDS pipe fills the QK MFMA drain)
    bf16x8 vf[2][4];
    #pragma unroll
    for (int nd = 0; nd < 2; ++nd)
      #pragma unroll
      for (int k2 = 0; k2 < 4; ++k2){
        const int row = nd*32 + l31;
        vf[nd][k2] = *(const bf16x8*)(kb + 8192 + row*128 + ((k2*32 + hgl*16) ^ ((row & 7) << 4)));
      }
    asm volatile("s_waitcnt lgkmcnt(0)" ::: "memory");
    __builtin_amdgcn_sched_barrier(0);

    // --- SM0 -> PV0 -> SM1 (VALU overlaps PV0's MFMAs) -> PV1 ---
    #pragma unroll
    for (int qt = 0; qt < 2; ++qt){
      #pragma unroll
      for (int kvt = 0; kvt < 2; ++kvt)
        #pragma unroll
        for (int r = 0; r < 16; ++r)
          sc[qt][kvt][r] = __builtin_amdgcn_exp2f(sc[qt][kvt][r]);
      f32x16 es = sc[qt][0] + sc[qt][1];
      float a0 = es[0]+es[8],  a1 = es[1]+es[9],  a2 = es[2]+es[10], a3 = es[3]+es[11];
      float a4 = es[4]+es[12], a5 = es[5]+es[13], a6 = es[6]+es[14], a7 = es[7]+es[15];
      float b0 = a0+a4, b1 = a1+a5, b2 = a2+a6, b3 = a3+a7;
      l_run[qt] += (b0+b1) + (b2+b3);

      u32x4 paw[4];
      #pragma unroll
      for (int kvt = 0; kvt < 2; ++kvt)
        #pragma unroll
        for (int k2r = 0; k2r < 2; ++k2r){
          u32 w0 = permpack(sc[qt][kvt][k2r*8+1], sc[qt][kvt][k2r*8+0]);
          u32 w1 = permpack(sc[qt][kvt][k2r*8+3], sc[qt][kvt][k2r*8+2]);
          u32 w2 = permpack(sc[qt][kvt][k2r*8+5], sc[qt][kvt][k2r*8+4]);
          u32 w3 = permpack(sc[qt][kvt][k2r*8+7], sc[qt][kvt][k2r*8+6]);
          asm("v_permlane32_swap_b32 %0, %1" : "+v"(w0), "+v"(w2));
          asm("v_permlane32_swap_b32 %0, %1" : "+v"(w1), "+v"(w3));
          const int k2 = kvt*2 + k2r;
          paw[k2][0] = w0; paw[k2][1] = w1;
          paw[k2][2] = w2; paw[k2][3] = w3;
        }

      #pragma unroll
      for (int nd = 0; nd < 2; ++nd)
        #pragma unroll
        for (int k2 = 0; k2 < 4; ++k2)
          o[qt][nd] = __builtin_amdgcn_mfma_f32_32x32x16_bf16(
              __builtin_bit_cast(bf16x8, paw[k2]), vf[nd][k2], o[qt][nd], 0, 0, 0);
    }
  }

  // ---- write bf16 partial (O, l) for this S-quarter ----
  #pragma unroll
  for (int qt = 0; qt < 2; ++qt){
    float lf = l_run[qt] + __shfl_xor(l_run[qt], 32);
    u16* Ob = Opart + ((size_t)sq * 32768 + (size_t)bh * 1024) * 64;
    #pragma unroll
    for (int nd = 0; nd < 2; ++nd)
      #pragma unroll
      for (int r = 0; r < 16; ++r){
        int q = qh*512 + w*64 + qt*32 + (r & 3) + 8*(r >> 2) + 4*hgl;
        Ob[(size_t)q * 64 + nd*32 + l31] = f2bf(o[qt][nd][r]);
      }
    if (hgl == 0)
      lpart[(size_t)sq * 32768 + (size_t)bh * 1024 + qh*512 + w*64 + qt*32 + l31] = lf;
  }
}

// ---------------- merge the 4 S-quarter partials -> AC bf16 ----------------
__global__ __launch_bounds__(256) void merge_kernel(
    const u16* __restrict__ Opart, const float* __restrict__ lpart,
    u16* __restrict__ AC)
{
  int idx = blockIdx.x * 256 + threadIdx.x;       // 262144 = 32768 rows x 8 dgroups
  int row = idx >> 3, dg = idx & 7;
  int bh = row >> 10, lq = row & 1023;
  int b = bh >> 4, h = bh & 15;
  float a[8];
  #pragma unroll
  for (int e = 0; e < 8; ++e) a[e] = 0.f;
  float lt = 0.f;
  #pragma unroll
  for (int p = 0; p < 4; ++p){
    u16x8 v = *(const u16x8*)(Opart + ((size_t)p * 32768 + row) * 64 + dg * 8);
    #pragma unroll
    for (int e = 0; e < 8; ++e)
      a[e] += __uint_as_float((u32)v[e] << 16);
    lt += lpart[(size_t)p * 32768 + row];
  }
  float rl = 1.0f / lt;
  u16x8 r;
  #pragma unroll
  for (int e = 0; e < 8; ++e) r[e] = f2bf(a[e] * rl);
  *(u16x8*)(AC + ((size_t)(b*LQ + lq)) * (Hh*DQK) + h*DQK + dg*8) = r;
}

// ---------------- host ----------------
extern "C" void kernel_launch(void* const* d_in, const int* in_sizes, int n_in,
                              void* d_out, int out_size, void* d_ws, size_t ws_size,
                              hipStream_t stream)
{
  (void)in_sizes; (void)n_in; (void)out_size; (void)ws_size;
  const float* x      = (const float*)d_in[0];
  const float* norm_w = (const float*)d_in[1];
  const float* wq_w   = (const float*)d_in[2];
  const float* wq_b   = (const float*)d_in[3];
  const float* wkv_w  = (const float*)d_in[4];
  const float* wkv_b  = (const float*)d_in[5];
  const float* wout_w = (const float*)d_in[6];
  const float* wout_b = (const float*)d_in[7];
  const float* wbyp_w = (const float*)d_in[8];
  float* outp = (float*)d_out;

  char* p = (char*)d_ws;
  u16* normb = (u16*)p; p += (size_t)8192*512*2;     // norm bf16 (B*S, D)
  u16* xb    = (u16*)p; p += (size_t)8192*512*2;     // x bf16
  u16* wtq   = (u16*)p; p += (size_t)1024*2048*2;    // wq^T  (N=1024, K=2048)
  u16* wtkv  = (u16*)p; p += (size_t)2048*512*2;     // wkv^T (N=2048, K=512)
  u16* wto   = (u16*)p; p += (size_t)1024*3072*2;    // [wout;wbyp]^T (N=1024, K=3072)
  u16* Qb    = (u16*)p; p += (size_t)32*1024*64*2;   // Q  (B,H, LQ, 64), pre-scaled
  u16* Kb    = (u16*)p; p += (size_t)32*4096*64*2;   // K  (B,H, S, 64)
  u16* Vtb   = (u16*)p; p += (size_t)32*64*4096*2;   // V^T (B,H, 64, S)
  u16* ACb   = (u16*)p; p += (size_t)2048*1024*2;    // attn_concat bf16
  float2* rtab = (float2*)p; p += (size_t)4096*32*sizeof(float2);
  u16* Opart = (u16*)p; p += (size_t)4*32768*64*2;   // [sq][bh][1024][64] bf16
  float* lpart = (float*)p; p += (size_t)4*32768*4;  // [sq][bh][1024]

  prep_kernel<<<4096, 256, 0, stream>>>(x, norm_w, wq_w, wkv_w, wout_w, wbyp_w,
                                        normb, xb, rtab, wtq, wtkv, wto);
  // fused Q-proj (64 blocks) + KV-proj (512 blocks), 256x128 tiles, 512 threads
  qkv_kernel<<<576, 512, 0, stream>>>(normb, wtq, wtkv, wq_b, wkv_b, rtab, Qb, Kb, Vtb);
  flash_kernel<<<256, 512, 0, stream>>>(Qb, Kb, Vtb, Opart, lpart);
  merge_kernel<<<1024, 256, 0, stream>>>(Opart, lpart, ACb);
  // OUT: M=2048, N=1024, K=3072 single k-split pass
  out_kernel<<<dim3(32,16), 256, 0, stream>>>(ACb, xb, wto, wout_b, outp);
}